// Round 1
// baseline (685.210 us; speedup 1.0000x reference)
//
#include <hip/hip_runtime.h>
#include <hip/hip_bf16.h>
#include <cstdint>

#define BATCH 1024
#define NPRE  8192
#define NPOST 8192

typedef _Float16 half8  __attribute__((ext_vector_type(8)));
typedef _Float16 half4_t __attribute__((ext_vector_type(4)));
typedef float    float4_t __attribute__((ext_vector_type(4)));

__device__ constexpr float ALPHA_SYN = 0.8187307530779818f; // exp(-0.001/0.005)
__device__ constexpr float DT_C = 0.001f;

// ---------------------------------------------------------------- prep
// A = spikes * U * x1   (f16, into ws)
// x_new = x1 * (1 - U*clip(spikes,0,1))  (f32, into d_out second half)
__global__ __launch_bounds__(256) void prep_kernel(
    const float* __restrict__ spikes, const float* __restrict__ x_std,
    const float* __restrict__ log_tau_rec, const float* __restrict__ logit_U,
    _Float16* __restrict__ Ah, float* __restrict__ x_new_out)
{
    const float tau_rec   = expf(log_tau_rec[0]);
    const float alpha_rec = expf(-DT_C / tau_rec);
    const float U         = 1.0f / (1.0f + expf(-logit_U[0]));

    const size_t i = ((size_t)blockIdx.x * 256 + threadIdx.x) * 4;
    float4_t sp = *(const float4_t*)(spikes + i);
    float4_t xs = *(const float4_t*)(x_std + i);
    float4_t xn;
    half4_t  a;
#pragma unroll
    for (int j = 0; j < 4; ++j) {
        float x1  = 1.0f - (1.0f - xs[j]) * alpha_rec;
        float av  = sp[j] * U * x1;
        a[j]      = (_Float16)av;
        float spc = fminf(fmaxf(sp[j], 0.0f), 1.0f);
        xn[j]     = x1 * (1.0f - U * spc);
    }
    *(half4_t*)(Ah + i)        = a;
    *(float4_t*)(x_new_out + i) = xn;
}

// ---------------------------------------------------------------- transpose
// W (f32, K x N, n contiguous) -> Wt (f16, N x K, k contiguous)
__global__ __launch_bounds__(256) void transpose_kernel(
    const float* __restrict__ W, _Float16* __restrict__ Wt)
{
    __shared__ float tile[64][65];   // +1 pad: conflict-light both directions
    const int n0 = blockIdx.x * 64;
    const int k0 = blockIdx.y * 64;
    const int t  = threadIdx.x;
    const int rr = t >> 4;   // 0..15
    const int cc = t & 15;   // 0..15
#pragma unroll
    for (int it = 0; it < 4; ++it) {
        const int r = it * 16 + rr;
        float4_t v = *(const float4_t*)(W + (size_t)(k0 + r) * NPOST + n0 + cc * 4);
        tile[r][cc * 4 + 0] = v[0];
        tile[r][cc * 4 + 1] = v[1];
        tile[r][cc * 4 + 2] = v[2];
        tile[r][cc * 4 + 3] = v[3];
    }
    __syncthreads();
    const int n  = t >> 2;         // 0..63
    const int kc = (t & 3) * 16;   // 0,16,32,48
    half8 h0, h1;
#pragma unroll
    for (int j = 0; j < 8; ++j) h0[j] = (_Float16)tile[kc + j][n];
#pragma unroll
    for (int j = 0; j < 8; ++j) h1[j] = (_Float16)tile[kc + 8 + j][n];
    _Float16* dst = Wt + (size_t)(n0 + n) * NPRE + k0 + kc;
    *(half8*)(dst)     = h0;
    *(half8*)(dst + 8) = h1;
}

// ---------------------------------------------------------------- GEMM
// C[m][n] = sum_k Ah[m][k] * Wt[n][k]; epilogue fuses noise + leak.
#define BM 128
#define BN 128
#define BK 64

__device__ __forceinline__ void gload_lds16(const void* g, void* l) {
    __builtin_amdgcn_global_load_lds(
        (const __attribute__((address_space(1))) void*)g,
        (__attribute__((address_space(3))) void*)l, 16, 0, 0);
}

__global__ __launch_bounds__(256, 2) void gemm_kernel(
    const _Float16* __restrict__ Ah, const _Float16* __restrict__ Wt,
    const float* __restrict__ I_syn, const float* __restrict__ noise,
    const float* __restrict__ log_strength, float* __restrict__ out)
{
    __shared__ _Float16 As[BM * BK];  // [row][k] linear, 128B rows
    __shared__ _Float16 Bs[BN * BK];

    const int tid  = threadIdx.x;
    const int lane = tid & 63;
    const int wid  = tid >> 6;   // 0..3
    const int wr   = wid >> 1;   // wave row 0..1
    const int wc   = wid & 1;    // wave col 0..1
    const int bm0  = blockIdx.y * BM;
    const int bn0  = blockIdx.x * BN;

    // staging: wave w covers rows [w*32, w*32+32), 4 calls x 8 rows each;
    // lane -> (row = lane>>3, 16B chunk = lane&7); LDS dest = base + lane*16 (HW)
    const int srow = wid * 32;
    const int r8   = lane >> 3;
    const int c8   = lane & 7;
    const _Float16* ag = Ah + (size_t)(bm0 + srow + r8) * NPRE + c8 * 8;
    const _Float16* bg = Wt + (size_t)(bn0 + srow + r8) * NPRE + c8 * 8;
    _Float16* al = As + srow * BK;
    _Float16* bl = Bs + srow * BK;

    float4_t acc[4][4];
#pragma unroll
    for (int m = 0; m < 4; ++m)
#pragma unroll
        for (int n = 0; n < 4; ++n) acc[m][n] = {0.f, 0.f, 0.f, 0.f};

    const int l16 = lane & 15;
    const int lq  = lane >> 4;

    for (int k0 = 0; k0 < NPRE; k0 += BK) {
#pragma unroll
        for (int i = 0; i < 4; ++i) {
            gload_lds16(ag + (size_t)i * 8 * NPRE + k0, al + i * 8 * BK);
            gload_lds16(bg + (size_t)i * 8 * NPRE + k0, bl + i * 8 * BK);
        }
        __syncthreads();   // drains vmcnt before any wave reads LDS
#pragma unroll
        for (int kk = 0; kk < 2; ++kk) {
            const int koff = kk * 32 + lq * 8;
            half8 af[4], bf[4];
#pragma unroll
            for (int m = 0; m < 4; ++m)
                af[m] = *(const half8*)(As + (wr * 64 + m * 16 + l16) * BK + koff);
#pragma unroll
            for (int n = 0; n < 4; ++n)
                bf[n] = *(const half8*)(Bs + (wc * 64 + n * 16 + l16) * BK + koff);
#pragma unroll
            for (int m = 0; m < 4; ++m)
#pragma unroll
                for (int n = 0; n < 4; ++n)
                    acc[m][n] = __builtin_amdgcn_mfma_f32_16x16x32_f16(
                        af[m], bf[n], acc[m][n], 0, 0, 0);
        }
        __syncthreads();   // protect LDS before next stage
    }

    const float s = expf(log_strength[0]);
#pragma unroll
    for (int m = 0; m < 4; ++m) {
#pragma unroll
        for (int n = 0; n < 4; ++n) {
            const int col = bn0 + wc * 64 + n * 16 + l16;
#pragma unroll
            for (int r = 0; r < 4; ++r) {
                const int row = bm0 + wr * 64 + m * 16 + lq * 4 + r; // m89-verified C/D layout
                const size_t idx = (size_t)row * NPOST + col;
                const float inj = acc[m][n][r] * s;
                out[idx] = I_syn[idx] * ALPHA_SYN + inj * (1.0f + noise[idx] * 0.15f);
            }
        }
    }
}

// ---------------------------------------------------------------- launch
extern "C" void kernel_launch(void* const* d_in, const int* in_sizes, int n_in,
                              void* d_out, int out_size, void* d_ws, size_t ws_size,
                              hipStream_t stream) {
    const float* spikes       = (const float*)d_in[0];
    const float* I_syn        = (const float*)d_in[1];
    const float* x_std        = (const float*)d_in[2];
    const float* noise        = (const float*)d_in[3];
    const float* Wnm          = (const float*)d_in[4];
    const float* log_strength = (const float*)d_in[5];
    const float* log_tau_rec  = (const float*)d_in[6];
    const float* logit_U      = (const float*)d_in[7];
    float* out = (float*)d_out;

    _Float16* Ah = (_Float16*)d_ws;                                            // 16 MB
    _Float16* Wt = (_Float16*)((char*)d_ws + (size_t)BATCH * NPRE * 2);        // 128 MB

    float* x_new_out = out + (size_t)BATCH * NPOST;

    prep_kernel<<<(BATCH * NPRE) / (256 * 4), 256, 0, stream>>>(
        spikes, x_std, log_tau_rec, logit_U, Ah, x_new_out);
    transpose_kernel<<<dim3(NPOST / 64, NPRE / 64), 256, 0, stream>>>(Wnm, Wt);
    gemm_kernel<<<dim3(NPOST / BN, BATCH / BM), 256, 0, stream>>>(
        Ah, Wt, I_syn, noise, log_strength, out);
}

// Round 3
// 683.484 us; speedup vs baseline: 1.0025x; 1.0025x over previous
//
#include <hip/hip_runtime.h>
#include <hip/hip_bf16.h>
#include <cstdint>

#define BATCH 1024
#define NPRE  8192
#define NPOST 8192

typedef _Float16 half8  __attribute__((ext_vector_type(8)));
typedef _Float16 half4_t __attribute__((ext_vector_type(4)));
typedef float    float4_t __attribute__((ext_vector_type(4)));

__device__ constexpr float ALPHA_SYN = 0.8187307530779818f; // exp(-0.001/0.005)
__device__ constexpr float DT_C = 0.001f;

// ---------------------------------------------------------------- prep
// A = spikes * U * x1   (f16, into ws)
// x_new = x1 * (1 - U*clip(spikes,0,1))  (f32, d_out second half)
// out[:8M] = I_syn * ALPHA_SYN  (prefill for split-K atomic accumulation)
__global__ __launch_bounds__(256) void prep_kernel(
    const float* __restrict__ spikes, const float* __restrict__ x_std,
    const float* __restrict__ I_syn,
    const float* __restrict__ log_tau_rec, const float* __restrict__ logit_U,
    _Float16* __restrict__ Ah, float* __restrict__ out)
{
    const float tau_rec   = expf(log_tau_rec[0]);
    const float alpha_rec = expf(-DT_C / tau_rec);
    const float U         = 1.0f / (1.0f + expf(-logit_U[0]));

    const size_t i = ((size_t)blockIdx.x * 256 + threadIdx.x) * 4;
    float4_t sp = *(const float4_t*)(spikes + i);
    float4_t xs = *(const float4_t*)(x_std + i);
    float4_t is = *(const float4_t*)(I_syn + i);
    float4_t xn, ipre;
    half4_t  a;
#pragma unroll
    for (int j = 0; j < 4; ++j) {
        float x1  = 1.0f - (1.0f - xs[j]) * alpha_rec;
        float av  = sp[j] * U * x1;
        a[j]      = (_Float16)av;
        float spc = fminf(fmaxf(sp[j], 0.0f), 1.0f);
        xn[j]     = x1 * (1.0f - U * spc);
        ipre[j]   = is[j] * ALPHA_SYN;
    }
    *(half4_t*)(Ah + i)                          = a;
    *(float4_t*)(out + (size_t)BATCH * NPOST + i) = xn;   // x_new
    *(float4_t*)(out + i)                         = ipre; // I_syn*alpha prefill
}

// ---------------------------------------------------------------- transpose
// W (f32, K x N, n contiguous) -> Wt (f16, N x K, k contiguous)
__global__ __launch_bounds__(256) void transpose_kernel(
    const float* __restrict__ W, _Float16* __restrict__ Wt)
{
    __shared__ float tile[64][65];
    const int n0 = blockIdx.x * 64;
    const int k0 = blockIdx.y * 64;
    const int t  = threadIdx.x;
    const int rr = t >> 4;
    const int cc = t & 15;
#pragma unroll
    for (int it = 0; it < 4; ++it) {
        const int r = it * 16 + rr;
        float4_t v = *(const float4_t*)(W + (size_t)(k0 + r) * NPOST + n0 + cc * 4);
        tile[r][cc * 4 + 0] = v[0];
        tile[r][cc * 4 + 1] = v[1];
        tile[r][cc * 4 + 2] = v[2];
        tile[r][cc * 4 + 3] = v[3];
    }
    __syncthreads();
    const int n  = t >> 2;
    const int kc = (t & 3) * 16;
    half8 h0, h1;
#pragma unroll
    for (int j = 0; j < 8; ++j) h0[j] = (_Float16)tile[kc + j][n];
#pragma unroll
    for (int j = 0; j < 8; ++j) h1[j] = (_Float16)tile[kc + 8 + j][n];
    _Float16* dst = Wt + (size_t)(n0 + n) * NPRE + k0 + kc;
    *(half8*)(dst)     = h0;
    *(half8*)(dst + 8) = h1;
}

// ---------------------------------------------------------------- GEMM
// Split-K=2, BK=32, double-buffered LDS, 2-phase pipeline.
// out[idx] += s * acc * (1 + 0.15*noise[idx])  via native f32 atomic.
#define BM 128
#define BN 128
#define BK 32
#define SPLITK 2
#define NT (NPRE / SPLITK / BK)   // 128 K-steps per block

__device__ __forceinline__ void gload_lds16(const _Float16* g, _Float16* l) {
    __builtin_amdgcn_global_load_lds(
        (const __attribute__((address_space(1))) void*)g,
        (__attribute__((address_space(3))) void*)l, 16, 0, 0);
}

__global__ __launch_bounds__(256, 4) void gemm_kernel(
    const _Float16* __restrict__ Ah, const _Float16* __restrict__ Wt,
    const float* __restrict__ noise,
    const float* __restrict__ log_strength, float* __restrict__ out)
{
    __shared__ _Float16 As[2][BM * BK];   // 8 KB each buffer
    __shared__ _Float16 Bs[2][BN * BK];

    const int tid  = threadIdx.x;
    const int lane = tid & 63;
    const int wid  = tid >> 6;
    const int wr   = wid >> 1;
    const int wc   = wid & 1;
    const int bm0  = blockIdx.y * BM;
    const int bn0  = blockIdx.x * BN;
    const int kbase = blockIdx.z * (NPRE / SPLITK);

    // staging geometry: chunk = j*256 + tid -> row = chunk>>2 (0..127),
    // piece = tid&3 (16B within 64B row). LDS dest wave-uniform base; HW adds lane*16.
    const int srow0  = tid >> 2;          // j=0 row
    const int piece  = tid & 3;
    const _Float16* agb = Ah + (size_t)(bm0 + srow0) * NPRE + kbase + piece * 8;
    const _Float16* bgb = Wt + (size_t)(bn0 + srow0) * NPRE + kbase + piece * 8;

    float4_t acc[4][4];
#pragma unroll
    for (int m = 0; m < 4; ++m)
#pragma unroll
        for (int n = 0; n < 4; ++n) acc[m][n] = {0.f, 0.f, 0.f, 0.f};

    const int l16 = lane & 15;
    const int lq  = lane >> 4;

#define STAGE(buf, kt)                                                        \
    {                                                                          \
        const int kg = (kt) * BK;                                              \
        _Pragma("unroll")                                                      \
        for (int j = 0; j < 2; ++j) {                                          \
            gload_lds16(agb + (size_t)j * 64 * NPRE + kg,                      \
                        &As[buf][(j * 256 + wid * 64) * 8]);                   \
            gload_lds16(bgb + (size_t)j * 64 * NPRE + kg,                      \
                        &Bs[buf][(j * 256 + wid * 64) * 8]);                   \
        }                                                                      \
    }

#define COMPUTE(buf)                                                           \
    {                                                                          \
        half8 af[4], bf[4];                                                    \
        _Pragma("unroll")                                                      \
        for (int m = 0; m < 4; ++m)                                            \
            af[m] = *(const half8*)&As[buf][(wr * 64 + m * 16 + l16) * BK + lq * 8]; \
        _Pragma("unroll")                                                      \
        for (int n = 0; n < 4; ++n)                                            \
            bf[n] = *(const half8*)&Bs[buf][(wc * 64 + n * 16 + l16) * BK + lq * 8]; \
        _Pragma("unroll")                                                      \
        for (int m = 0; m < 4; ++m)                                            \
            _Pragma("unroll")                                                  \
            for (int n = 0; n < 4; ++n)                                        \
                acc[m][n] = __builtin_amdgcn_mfma_f32_16x16x32_f16(            \
                    af[m], bf[n], acc[m][n], 0, 0, 0);                         \
    }

    STAGE(0, 0);
    __syncthreads();
    int cur = 0;
    for (int t = 0; t < NT - 1; ++t) {
        STAGE(cur ^ 1, t + 1);   // issue next-tile async loads first
        COMPUTE(cur);            // ds_read + MFMA on current buffer
        __syncthreads();         // drains vmcnt (stage done) + all reads done
        cur ^= 1;
    }
    COMPUTE(cur);

    const float s = expf(log_strength[0]);
#pragma unroll
    for (int m = 0; m < 4; ++m) {
#pragma unroll
        for (int n = 0; n < 4; ++n) {
            const int col = bn0 + wc * 64 + n * 16 + l16;
#pragma unroll
            for (int r = 0; r < 4; ++r) {
                const int row = bm0 + wr * 64 + m * 16 + lq * 4 + r;
                const size_t idx = (size_t)row * NPOST + col;
                const float v = acc[m][n][r] * s * (1.0f + noise[idx] * 0.15f);
                unsafeAtomicAdd(&out[idx], v);
            }
        }
    }
#undef STAGE
#undef COMPUTE
}

// ---------------------------------------------------------------- launch
extern "C" void kernel_launch(void* const* d_in, const int* in_sizes, int n_in,
                              void* d_out, int out_size, void* d_ws, size_t ws_size,
                              hipStream_t stream) {
    const float* spikes       = (const float*)d_in[0];
    const float* I_syn        = (const float*)d_in[1];
    const float* x_std        = (const float*)d_in[2];
    const float* noise        = (const float*)d_in[3];
    const float* Wnm          = (const float*)d_in[4];
    const float* log_strength = (const float*)d_in[5];
    const float* log_tau_rec  = (const float*)d_in[6];
    const float* logit_U      = (const float*)d_in[7];
    float* out = (float*)d_out;

    _Float16* Ah = (_Float16*)d_ws;                                     // 16 MB
    _Float16* Wt = (_Float16*)((char*)d_ws + (size_t)BATCH * NPRE * 2); // 128 MB

    prep_kernel<<<(BATCH * NPRE) / (256 * 4), 256, 0, stream>>>(
        spikes, x_std, I_syn, log_tau_rec, logit_U, Ah, out);
    transpose_kernel<<<dim3(NPOST / 64, NPRE / 64), 256, 0, stream>>>(Wnm, Wt);
    gemm_kernel<<<dim3(NPOST / BN, BATCH / BM, SPLITK), 256, 0, stream>>>(
        Ah, Wt, noise, log_strength, out);
}